// Round 5
// baseline (139.566 us; speedup 1.0000x reference)
//
#include <hip/hip_runtime.h>

typedef __bf16 bf16_t;
typedef bf16_t bf16x8 __attribute__((ext_vector_type(8)));
typedef float f32x4 __attribute__((ext_vector_type(4)));

#define NSEQ 2048
#define EMB 512
#define HEADS 8
#define HD 64
#define BATCH 4
#define LOG2E 1.4426950408889634f

#define MFMA16(a, b, c) __builtin_amdgcn_mfma_f32_16x16x32_bf16(a, b, c, 0, 0, 0)

// ---------------------------------------------------------------------------
// Fused K/V projection GEMM with inline fp32->bf16 convert (unchanged R4):
// C[8192,1024] = x @ [Wk;Wv]^T + [bk;bv]. 128x128 tile, BK=64, register-
// prefetch pipeline, kk-split pitch-40 LDS. Transpose epilogue -> coalesced
// Kh[b][h][n][d] / Vt[b][h][d][n] stores.
// ---------------------------------------------------------------------------
__global__ __launch_bounds__(256, 2) void proj_kernel(
    const float* __restrict__ x,
    const float* __restrict__ Wk, const float* __restrict__ bk,
    const float* __restrict__ Wv, const float* __restrict__ bv,
    bf16_t* __restrict__ Kh, bf16_t* __restrict__ Vt)
{
  __shared__ union {
    struct {
      __align__(16) bf16_t A[2][128][40];   // [kk-half][row][32 el + pad]
      __align__(16) bf16_t B[2][128][40];
    } s;
    __align__(16) bf16_t T[128][136];       // epilogue transpose buffer
  } u;

  const int t    = threadIdx.x;
  const int w    = t >> 6;
  const int lane = t & 63;
  const int quad = lane >> 4;
  const int l15  = lane & 15;
  const int wr   = w >> 1, wc = w & 1;
  const int m0   = blockIdx.x * 128;
  const int n0   = blockIdx.y * 128;        // stacked feature base 0..896
  const int zz   = (blockIdx.y >= 4);       // 0: K-features, 1: V-features
  const float* __restrict__ W = zz ? Wv : Wk;
  const int nW = n0 - zz * 512;             // row base within W

  const int sr = t >> 3;        // staging row 0..31 (x4 groups)
  const int sj = t & 7;         // 8-el chunk 0..7 within 64-el k slab
  const int sb = sj >> 2, sc = (sj & 3) * 8;

  float4 pa[4][2], pb[4][2];
  auto prefetch = [&](int k0) {
#pragma unroll
    for (int i = 0; i < 4; ++i) {
      const float* xa = x + (size_t)(m0 + sr + i * 32) * EMB + k0 + sj * 8;
      const float* wa = W + (size_t)(nW + sr + i * 32) * EMB + k0 + sj * 8;
      pa[i][0] = *(const float4*)xa; pa[i][1] = *(const float4*)(xa + 4);
      pb[i][0] = *(const float4*)wa; pb[i][1] = *(const float4*)(wa + 4);
    }
  };
  auto pack8 = [](float4 a, float4 b) -> bf16x8 {
    bf16x8 v;
    v[0] = (bf16_t)a.x; v[1] = (bf16_t)a.y; v[2] = (bf16_t)a.z; v[3] = (bf16_t)a.w;
    v[4] = (bf16_t)b.x; v[5] = (bf16_t)b.y; v[6] = (bf16_t)b.z; v[7] = (bf16_t)b.w;
    return v;
  };

  f32x4 acc[4][4] = {};
  prefetch(0);

  for (int it = 0; it < 8; ++it) {
    __syncthreads();
#pragma unroll
    for (int i = 0; i < 4; ++i) {
      *(bf16x8*)(&u.s.A[sb][sr + i * 32][sc]) = pack8(pa[i][0], pa[i][1]);
      *(bf16x8*)(&u.s.B[sb][sr + i * 32][sc]) = pack8(pb[i][0], pb[i][1]);
    }
    __syncthreads();
    if (it < 7) prefetch((it + 1) * 64);

    bf16x8 af[4][2], bf[4][2];
#pragma unroll
    for (int mt = 0; mt < 4; ++mt)
#pragma unroll
      for (int kk = 0; kk < 2; ++kk)
        af[mt][kk] = *(const bf16x8*)(&u.s.A[kk][wr * 64 + mt * 16 + l15][quad * 8]);
#pragma unroll
    for (int nt = 0; nt < 4; ++nt)
#pragma unroll
      for (int kk = 0; kk < 2; ++kk)
        bf[nt][kk] = *(const bf16x8*)(&u.s.B[kk][wc * 64 + nt * 16 + l15][quad * 8]);
#pragma unroll
    for (int kk = 0; kk < 2; ++kk)
#pragma unroll
      for (int mt = 0; mt < 4; ++mt)
#pragma unroll
        for (int nt = 0; nt < 4; ++nt)
          acc[mt][nt] = MFMA16(af[mt][kk], bf[nt][kk], acc[mt][nt]);
  }

  __syncthreads();  // staging LDS -> transpose buffer reuse

  // Stage 1: +bias, bf16, into LDS in output-major layout.
#pragma unroll
  for (int mt = 0; mt < 4; ++mt) {
#pragma unroll
    for (int nt = 0; nt < 4; ++nt) {
      const int F = wc * 64 + nt * 16 + l15;       // local feature 0..127
      const int c = n0 + F;                        // stacked feature 0..1023
      const float bb = zz ? bv[c - 512] : bk[c];
#pragma unroll
      for (int reg = 0; reg < 4; ++reg) {
        const int R = wr * 64 + mt * 16 + quad * 4 + reg;  // local row 0..127
        const float v = acc[mt][nt][reg] + bb;
        if (!zz) u.T[R][F] = (bf16_t)v;   // Kh: [n][feat]
        else     u.T[F][R] = (bf16_t)v;   // Vt: [feat][n]
      }
    }
  }
  __syncthreads();

  // Stage 2: coalesced bf16x8 stores.
#pragma unroll
  for (int i = 0; i < 8; ++i) {
    const int q  = t + i * 256;       // 0..2047
    const int R  = q >> 4;            // LDS row 0..127
    const int C8 = (q & 15) * 8;      // LDS col chunk
    const bf16x8 v = *(const bf16x8*)(&u.T[R][C8]);
    if (!zz) {
      const int gr = m0 + R, b = gr >> 11, n = gr & (NSEQ - 1);
      const int c = n0 + C8, hh = c >> 6, d = c & 63;
      *(bf16x8*)(Kh + (((size_t)(b * HEADS + hh)) * NSEQ + n) * HD + d) = v;
    } else {
      const int cv = n0 + R - 512, hh = cv >> 6, d = cv & 63;
      const int gr = m0 + C8, b = gr >> 11, n = gr & (NSEQ - 1);
      *(bf16x8*)(Vt + (((size_t)(b * HEADS + hh)) * HD + d) * NSEQ + n) = v;
    }
  }
}

// ---------------------------------------------------------------------------
// Flash attention, Q = K, fixed max m_i = ||k_i||^2 (validated R2-R4).
// S^T trick (validated R4): S^T = K.Q^T so C-col = q-row, P stores are b64.
// NEW (R5): each wave stages its OWN K-half / V-tile into PRIVATE LDS ->
// ZERO barriers in the main loop; waves free-run and hide each other's
// VMEM/LDS latency. Global K/V traffic doubles (irrelevant: ~2% HBM peak).
// Wave = 64 q-rows x 32 keys; 2x2 wave split (row-half x key-half);
// one barrier total (before the split-K combine). Grid (32 bh, 16) = 512.
// ---------------------------------------------------------------------------
__global__ __launch_bounds__(256, 2) void flash_kernel(
    const bf16_t* __restrict__ Kh, const bf16_t* __restrict__ Vt,
    float* __restrict__ out)
{
  __shared__ union {
    struct {
      __align__(16) bf16_t K[4][2][32][40];  // per-wave [kk][key][32 el + pad]
      __align__(16) bf16_t V[4][64][40];     // per-wave [d][32 keys + pad]
      __align__(16) bf16_t P[4][64][40];     // per-wave [qrow][32 keys + pad]
    } s;
    struct {
      __align__(16) float Cb[2][4096];       // key-half-1 O partials
      __align__(16) float Lb[2][64][4];      // key-half-1 l partials
    } c;
  } u;

  const int t    = threadIdx.x;
  const int w    = t >> 6;
  const int lane = t & 63;
  const int quad = lane >> 4;
  const int l15  = lane & 15;
  const int rh   = w & 1;              // row-half
  const int kh   = w >> 1;             // key-half

  const int bh = blockIdx.x;           // 0..31 (id%8 = bh%8 -> XCD locality)
  const int b  = bh >> 3, h = bh & 7;
  const int rowbase = blockIdx.y * 128 + rh * 64;

  const bf16_t* __restrict__ Kb = Kh + (size_t)bh * NSEQ * HD;
  const bf16_t* __restrict__ Vb = Vt + (size_t)bh * HD * NSEQ;

  // Resident Q fragments: qf[nt] = A-frag of Q rows (== B-frag of Q^T).
  bf16x8 qf[4][2];
#pragma unroll
  for (int nt = 0; nt < 4; ++nt)
#pragma unroll
    for (int kk = 0; kk < 2; ++kk)
      qf[nt][kk] = *(const bf16x8*)(Kb + (size_t)(rowbase + nt * 16 + l15) * HD +
                                    kk * 32 + quad * 8);

  // Fixed max m_i = ||k_i||^2; lane's q-row for tile nt is nt*16+l15.
  float mlog[4];
#pragma unroll
  for (int nt = 0; nt < 4; ++nt) {
    float ss = 0.f;
#pragma unroll
    for (int kk = 0; kk < 2; ++kk)
#pragma unroll
      for (int j = 0; j < 8; ++j) {
        const float qv = (float)qf[nt][kk][j];
        ss = fmaf(qv, qv, ss);
      }
    ss += __shfl_xor(ss, 16, 64);
    ss += __shfl_xor(ss, 32, 64);
    mlog[nt] = ss * LOG2E;
  }

  // Per-wave staging indices.
  const int skr = lane >> 3;           // K: row 0..7 within 8-row group
  const int skc = lane & 7;            // K: 8-el chunk 0..7 (64 els/row)
  const int skk = skc >> 2;            // K: kk half
  const int sk8 = (skc & 3) * 8;       // K: col within half
  const int svd = lane >> 2;           // V: d 0..15 within 16-row group
  const int svc = (lane & 3) * 8;      // V: key-col 0,8,16,24

  bf16x8 pk[4], pv[4];
  auto prefetch = [&](int kt) {
    const bf16_t* Kt = Kb + ((size_t)kt * 64 + kh * 32) * HD;  // contig 4 KB
    const bf16_t* Vp = Vb + (size_t)kt * 64 + kh * 32;
#pragma unroll
    for (int i = 0; i < 4; ++i) {
      pk[i] = *(const bf16x8*)(Kt + (size_t)(skr + i * 8) * HD + skc * 8);
      pv[i] = *(const bf16x8*)(Vp + (size_t)(svd + i * 16) * NSEQ + (lane & 3) * 8);
    }
  };

  f32x4 acco[4][4] = {};                 // [row-tile][d-tile]
  float lsum[4] = {0.f, 0.f, 0.f, 0.f};  // per q-row-tile, partial over lanes

  prefetch(0);

  for (int kt = 0; kt < NSEQ / 64; ++kt) {
    // Store prefetched tile into this wave's private LDS (no barrier).
#pragma unroll
    for (int i = 0; i < 4; ++i) {
      *(bf16x8*)(&u.s.K[w][skk][skr + i * 8][sk8]) = pk[i];
      *(bf16x8*)(&u.s.V[w][svd + i * 16][svc])     = pv[i];
    }
    if (kt + 1 < NSEQ / 64) prefetch(kt + 1);

    // S^T = K . Q^T over this wave's 32-key half.
    bf16x8 kf[2][2];
#pragma unroll
    for (int jt = 0; jt < 2; ++jt)
#pragma unroll
      for (int kk = 0; kk < 2; ++kk)
        kf[jt][kk] = *(const bf16x8*)(&u.s.K[w][kk][jt * 16 + l15][quad * 8]);

    f32x4 st[2][4] = {};
#pragma unroll
    for (int kk = 0; kk < 2; ++kk)
#pragma unroll
      for (int jt = 0; jt < 2; ++jt)
#pragma unroll
        for (int nt = 0; nt < 4; ++nt)
          st[jt][nt] = MFMA16(kf[jt][kk], qf[nt][kk], st[jt][nt]);

    // P = exp(S - m); lane: q-row nt*16+l15, keys jt*16+quad*4+reg -> b64.
#pragma unroll
    for (int jt = 0; jt < 2; ++jt)
#pragma unroll
      for (int nt = 0; nt < 4; ++nt) {
        union { bf16_t hx[4]; uint2 u2; } pw;
#pragma unroll
        for (int reg = 0; reg < 4; ++reg) {
          const float p =
              __builtin_amdgcn_exp2f(fmaf(st[jt][nt][reg], LOG2E, -mlog[nt]));
          lsum[nt] += p;
          pw.hx[reg] = (bf16_t)p;
        }
        *(uint2*)(&u.s.P[w][nt * 16 + l15][jt * 16 + quad * 4]) = pw.u2;
      }

    // O += P V over the 32-key half (K-dim = 32 = one MFMA step).
    bf16x8 vf[4];
#pragma unroll
    for (int dt = 0; dt < 4; ++dt)
      vf[dt] = *(const bf16x8*)(&u.s.V[w][dt * 16 + l15][quad * 8]);
#pragma unroll
    for (int rt = 0; rt < 4; ++rt) {
      const bf16x8 pf = *(const bf16x8*)(&u.s.P[w][rt * 16 + l15][quad * 8]);
#pragma unroll
      for (int dt = 0; dt < 4; ++dt)
        acco[rt][dt] = MFMA16(pf, vf[dt], acco[rt][dt]);
    }
  }

  // Split-K combine: key-half-1 waves dump partials; key-half-0 waves add.
  __syncthreads();
  if (kh == 1) {
#pragma unroll
    for (int rt = 0; rt < 4; ++rt)
#pragma unroll
      for (int dt = 0; dt < 4; ++dt)
        *(f32x4*)(&u.c.Cb[rh][((rt * 4 + dt) * 64 + lane) * 4]) = acco[rt][dt];
#pragma unroll
    for (int nt = 0; nt < 4; ++nt) u.c.Lb[rh][lane][nt] = lsum[nt];
  }
  __syncthreads();
  if (kh == 0) {
#pragma unroll
    for (int rt = 0; rt < 4; ++rt)
#pragma unroll
      for (int dt = 0; dt < 4; ++dt) {
        const f32x4 o = *(const f32x4*)(&u.c.Cb[rh][((rt * 4 + dt) * 64 + lane) * 4]);
        acco[rt][dt] += o;
      }
#pragma unroll
    for (int nt = 0; nt < 4; ++nt) {
      lsum[nt] += u.c.Lb[rh][lane][nt];
      lsum[nt] += __shfl_xor(lsum[nt], 16, 64);
      lsum[nt] += __shfl_xor(lsum[nt], 32, 64);
    }

    const float SCL = 0.044194173824159216f;  // 1/sqrt(512)
#pragma unroll
    for (int rt = 0; rt < 4; ++rt)
#pragma unroll
      for (int reg = 0; reg < 4; ++reg) {
        // O C-layout row = rt*16+quad*4+reg; its l lives at lane l15=quad*4+reg.
        const float lr = __shfl(lsum[rt], quad * 4 + reg, 64);
        const float f = SCL / lr;
        const int n = rowbase + rt * 16 + quad * 4 + reg;
#pragma unroll
        for (int dt = 0; dt < 4; ++dt)
          out[((size_t)(b * NSEQ + n)) * EMB + h * HD + dt * 16 + l15] =
              acco[rt][dt][reg] * f;
      }
  }
}

extern "C" void kernel_launch(void* const* d_in, const int* in_sizes, int n_in,
                              void* d_out, int out_size, void* d_ws, size_t ws_size,
                              hipStream_t stream) {
  const float* x  = (const float*)d_in[0];
  const float* Wk = (const float*)d_in[1];
  const float* bk = (const float*)d_in[2];
  const float* Wv = (const float*)d_in[3];
  const float* bv = (const float*)d_in[4];
  float* out = (float*)d_out;

  bf16_t* Kh = (bf16_t*)d_ws;                                   // 8 MB
  bf16_t* Vt = Kh + (size_t)BATCH * HEADS * NSEQ * HD;          // 8 MB

  dim3 pg(8192 / 128, 1024 / 128);
  proj_kernel<<<pg, 256, 0, stream>>>(x, Wk, bk, Wv, bv, Kh, Vt);

  dim3 fg(BATCH * HEADS, NSEQ / 128);
  flash_kernel<<<fg, 256, 0, stream>>>(Kh, Vt, out);
}